// Round 8
// baseline (317.723 us; speedup 1.0000x reference)
//
#include <hip/hip_runtime.h>
#include <math.h>

#define BB 2
#define SS 2048
#define DD 1024
#define HH 16
#define FFDIM 4096
#define NROWS 4096

typedef short bf16x8 __attribute__((ext_vector_type(8)));
typedef float f32x4 __attribute__((ext_vector_type(4)));

__device__ __forceinline__ unsigned short f2bf(float f) {
    unsigned u = __float_as_uint(f);
    u += 0x7fffu + ((u >> 16) & 1u);
    return (unsigned short)(u >> 16);
}
__device__ __forceinline__ float bf2f(unsigned short s) {
    return __uint_as_float(((unsigned)s) << 16);
}

typedef __attribute__((address_space(1))) void gvoid;
typedef __attribute__((address_space(3))) void lvoid;
__device__ __forceinline__ void glds16(const void* g, void* l) {
    __builtin_amdgcn_global_load_lds((gvoid*)g, (lvoid*)l, 16, 0, 0);
}

// virtual key order: within each 32-key group, actual (16*t + quad*4 + r) sits at
// virtual (quad*8 + 4*t + r), t in {0,1}.
__device__ __forceinline__ int vkey(int kloc) {   // kloc % 4 == 0
    return (kloc & ~31) + ((kloc & 12) << 1) + ((kloc & 16) >> 2);
}

// ---------------- LN body (one block, row of 1024, fp32 -> bf16) -----------------
__device__ __forceinline__ void ln_body(const float* __restrict__ x,
                                        const float* __restrict__ g,
                                        const float* __restrict__ b,
                                        unsigned short* __restrict__ out, int row) {
    const float* xr = x + (size_t)row * DD;
    unsigned short* orow = out + (size_t)row * DD;
    int t = threadIdx.x;
    float4 v = ((const float4*)xr)[t];
    float s  = v.x + v.y + v.z + v.w;
    float s2 = v.x*v.x + v.y*v.y + v.z*v.z + v.w*v.w;
    #pragma unroll
    for (int off = 32; off > 0; off >>= 1) {
        s  += __shfl_down(s,  off);
        s2 += __shfl_down(s2, off);
    }
    __shared__ float red1[4], red2[4];
    int wid = t >> 6, lane = t & 63;
    if (lane == 0) { red1[wid] = s; red2[wid] = s2; }
    __syncthreads();
    if (t == 0) {
        float a = 0.f, a2 = 0.f;
        #pragma unroll
        for (int i = 0; i < 4; ++i) { a += red1[i]; a2 += red2[i]; }
        red1[0] = a; red2[0] = a2;
    }
    __syncthreads();
    float mean = red1[0] * (1.0f / DD);
    float var  = red2[0] * (1.0f / DD) - mean * mean;
    float rs = rsqrtf(var + 1e-5f);
    float4 gv = ((const float4*)g)[t];
    float4 bv = ((const float4*)b)[t];
    ushort4 o;
    o.x = f2bf((v.x - mean) * rs * gv.x + bv.x);
    o.y = f2bf((v.y - mean) * rs * gv.y + bv.y);
    o.z = f2bf((v.z - mean) * rs * gv.z + bv.z);
    o.w = f2bf((v.w - mean) * rs * gv.w + bv.w);
    ((ushort4*)orow)[t] = o;
}

__global__ __launch_bounds__(256) void ln_kernel(const float* __restrict__ x,
                                                 const float* __restrict__ g,
                                                 const float* __restrict__ b,
                                                 unsigned short* __restrict__ out) {
    ln_body(x, g, b, out, blockIdx.x);
}

// ---------------- prep: LN1 (blocks 0..4095) + 4 weight casts --------------------
__global__ __launch_bounds__(256) void prep_kernel(
    const float* __restrict__ x, const float* __restrict__ g1,
    const float* __restrict__ b1, unsigned short* __restrict__ hb,
    const float* __restrict__ a, unsigned short* __restrict__ oa,
    const float* __restrict__ b, unsigned short* __restrict__ ob,
    const float* __restrict__ c, unsigned short* __restrict__ oc,
    const float* __restrict__ d, unsigned short* __restrict__ od) {
    if (blockIdx.x < 4096) { ln_body(x, g1, b1, hb, blockIdx.x); return; }
    int i = (blockIdx.x - 4096) * 256 + threadIdx.x;
    const float* src; unsigned short* dst; int off;
    if (i < 786432)       { src = a; dst = oa; off = i; }
    else if (i < 1048576) { src = b; dst = ob; off = i - 786432; }
    else if (i < 2097152) { src = c; dst = oc; off = i - 1048576; }
    else                  { src = d; dst = od; off = i - 2097152; }
    float4 v = ((const float4*)src)[off];
    ushort4 o;
    o.x = f2bf(v.x); o.y = f2bf(v.y); o.z = f2bf(v.z); o.w = f2bf(v.w);
    ((ushort4*)dst)[off] = o;
}

// ---------------- final reduce: out = x1 + P0 + P1 + bias (P bf16) ---------------
__global__ __launch_bounds__(256) void reduce_add(const float* __restrict__ x1,
                                                  const unsigned short* __restrict__ P0,
                                                  const unsigned short* __restrict__ P1,
                                                  const float* __restrict__ bias,
                                                  float* __restrict__ out) {
    int i = blockIdx.x * 256 + threadIdx.x;      // float4 index over 4096x1024
    float4 a = ((const float4*)x1)[i];
    ushort4 p = ((const ushort4*)P0)[i];
    ushort4 q = ((const ushort4*)P1)[i];
    float4 bv = ((const float4*)bias)[i & 255];
    float4 o;
    o.x = a.x + bf2f(p.x) + bf2f(q.x) + bv.x;
    o.y = a.y + bf2f(p.y) + bf2f(q.y) + bv.y;
    o.z = a.z + bf2f(p.z) + bf2f(q.z) + bv.z;
    o.w = a.w + bf2f(p.w) + bf2f(q.w) + bv.w;
    ((float4*)out)[i] = o;
}

// ---------------- bf16 MFMA NT GEMM, tile 128 x TN -------------------------------
// VT: QKV mode; CS: coalesced bf16 store via LDS (FF1); SPLITK: 2-way K-split with
// bf16 partials; SWZ: XCD-locality block remap (same M-band -> same XCD).
template<int ACT, int RES, int OUTBF, int TN, int VT, int CS, int SPLITK, int SWZ>
__global__ __launch_bounds__(256, 3) void gemm_nt_mfma(
    const unsigned short* __restrict__ A,
    const unsigned short* __restrict__ W,
    const float* __restrict__ bias,
    const float* __restrict__ res,
    void* __restrict__ Cout,
    void* __restrict__ Cout2,
    unsigned short* __restrict__ Vtg,
    int M, int N, int K)
{
    constexpr int MI = (TN == 128) ? 4 : 2;
    constexpr int WR = TN / 4;
    __shared__ unsigned short SMEM[128 * 64 + TN * 64];
    unsigned short* As = SMEM;
    unsigned short* Ws = SMEM + 128 * 64;
    int tid = threadIdx.x;
    int lane = tid & 63;
    int w = tid >> 6;
    int rowbase = (TN == 128) ? ((w >> 1) * 64) : (w * 32);
    int colbase = (TN == 128) ? ((w & 1) * 64) : 0;
    int col16 = lane & 15, quad = lane >> 4;

    int bx, by, bz;
    if constexpr (SWZ) {
        // assumes round-robin block->XCD; keeps all (n,z) of an M-band on one XCD
        int nx = gridDim.x, nz = gridDim.z;
        int bid = blockIdx.x + nx * (blockIdx.y + 32 * blockIdx.z);
        int xcd = bid & 7;
        int g = bid >> 3;
        int per = nx * nz;
        by = xcd + 8 * (g / per);
        int r = g % per;
        bx = r % nx;
        bz = r / nx;
    } else { bx = blockIdx.x; by = blockIdx.y; bz = blockIdx.z; }
    int bm = by * 128, bn = bx * TN;

    int klen = SPLITK ? (K >> 1) : K;
    int kbase = SPLITK ? (bz * klen) : 0;

    f32x4 acc[MI][4] = {};

    int lrow = lane >> 3;
    int sw = (lane & 7) ^ lrow;
    const unsigned short* Ag = A + (size_t)(bm + w * 32 + lrow) * K + sw * 8;
    const unsigned short* Wg = W + (size_t)(bn + w * WR + lrow) * K + sw * 8;

    for (int k0 = kbase; k0 < kbase + klen; k0 += 64) {
        if (k0 != kbase) __syncthreads();
        #pragma unroll
        for (int it = 0; it < 4; ++it)
            glds16(Ag + (size_t)(8 * it) * K + k0, &As[(w * 32 + 8 * it) * 64]);
        #pragma unroll
        for (int it = 0; it < WR / 8; ++it)
            glds16(Wg + (size_t)(8 * it) * K + k0, &Ws[(w * WR + 8 * it) * 64]);
        __syncthreads();
        #pragma unroll
        for (int c = 0; c < 2; ++c) {
            bf16x8 af[MI], bfr[4];
            #pragma unroll
            for (int i = 0; i < MI; ++i) {
                int m = rowbase + i * 16 + col16;
                af[i] = *(const bf16x8*)&As[m * 64 + (((c * 4 + quad) ^ (m & 7)) * 8)];
            }
            #pragma unroll
            for (int j = 0; j < 4; ++j) {
                int n = colbase + j * 16 + col16;
                bfr[j] = *(const bf16x8*)&Ws[n * 64 + (((c * 4 + quad) ^ (n & 7)) * 8)];
            }
            #pragma unroll
            for (int i = 0; i < MI; ++i)
                #pragma unroll
                for (int j = 0; j < 4; ++j)
                    acc[i][j] = __builtin_amdgcn_mfma_f32_16x16x32_bf16(af[i], bfr[j], acc[i][j], 0, 0, 0);
        }
    }

    if constexpr (SPLITK) {
        unsigned short* P = (unsigned short*)(bz ? Cout2 : Cout);
        #pragma unroll
        for (int i = 0; i < MI; ++i) {
            #pragma unroll
            for (int j = 0; j < 4; ++j) {
                int nn = bn + colbase + j * 16 + col16;
                #pragma unroll
                for (int r = 0; r < 4; ++r) {
                    int mm = bm + rowbase + i * 16 + quad * 4 + r;
                    P[(size_t)mm * N + nn] = f2bf(acc[i][j][r]);
                }
            }
        }
        return;
    }

    if constexpr (CS) {
        // ---- FF1: bias+gelu -> LDS (swizzled) -> coalesced b128 stores ----
        __syncthreads();
        #pragma unroll
        for (int i = 0; i < MI; ++i) {
            #pragma unroll
            for (int j = 0; j < 4; ++j) {
                int nl = colbase + j * 16 + col16;
                float bv = bias[bn + nl];
                int c = nl >> 4;
                #pragma unroll
                for (int r = 0; r < 4; ++r) {
                    int ml = rowbase + i * 16 + quad * 4 + r;
                    float v = acc[i][j][r] + bv;
                    if (ACT) {
                        float z = v * (1.595769122f + 0.071354816f * v * v);
                        float e = __builtin_amdgcn_exp2f(-z * 1.442695041f);
                        v = v * __builtin_amdgcn_rcpf(1.0f + e);
                    }
                    SMEM[ml * 128 + ((c ^ ((ml >> 2) & 7)) << 4) + (nl & 15)] = f2bf(v);
                }
            }
        }
        __syncthreads();
        #pragma unroll
        for (int p = 0; p < 8; ++p) {
            int cid = tid + p * 256;
            int row = cid >> 4, cc = cid & 15;
            int cs2 = cc >> 1;
            bf16x8 vv = *(bf16x8*)&SMEM[row * 128 + ((cs2 ^ ((row >> 2) & 7)) << 4) + (cc & 1) * 8];
            *(bf16x8*)&((unsigned short*)Cout)[(size_t)(bm + row) * N + bn + cc * 8] = vv;
        }
        return;
    }

    bool wave_v = VT && ((((bn + colbase) >> 6) % 3) == 2);
    if constexpr (VT) __syncthreads();

    #pragma unroll
    for (int i = 0; i < MI; ++i) {
        #pragma unroll
        for (int j = 0; j < 4; ++j) {
            int nn = bn + colbase + j * 16 + col16;
            float bv = bias[nn];
            float vv[4];
            #pragma unroll
            for (int r = 0; r < 4; ++r) {
                float v = acc[i][j][r] + bv;
                if (ACT) {
                    float z = v * (1.595769122f + 0.071354816f * v * v);
                    float e = __builtin_amdgcn_exp2f(-z * 1.442695041f);
                    v = v * __builtin_amdgcn_rcpf(1.0f + e);
                }
                vv[r] = v;
            }
            int mm0 = bm + rowbase + i * 16 + quad * 4;
            if (VT && wave_v) {
                int d = j * 16 + col16;
                int kloc = rowbase + i * 16 + quad * 4;
                int vl = vkey(kloc);
                int ch = vl >> 3;
                ushort4 pk;
                pk.x = f2bf(vv[0]); pk.y = f2bf(vv[1]);
                pk.z = f2bf(vv[2]); pk.w = f2bf(vv[3]);
                *(ushort4*)&SMEM[d * 128 + ((ch ^ (d & 7)) << 3) + (vl & 7)] = pk;
            } else {
                #pragma unroll
                for (int r = 0; r < 4; ++r) {
                    int mm = mm0 + r;
                    float v = vv[r];
                    if (RES) v += res[(size_t)mm * N + nn];
                    if (OUTBF) ((unsigned short*)Cout)[(size_t)mm * N + nn] = f2bf(v);
                    else       ((float*)Cout)[(size_t)mm * N + nn] = v;
                }
            }
        }
    }

    if constexpr (VT) {
        __syncthreads();
        bool g0v = ((bn >> 6) % 3) == 2;
        bool g1v = (((bn + 64) >> 6) % 3) == 2;
        if (g0v || g1v) {
            int vcb = g0v ? 0 : 64;
            int hh = (bn + vcb) / 192;
            int bb = bm >> 11, sr = bm & 2047;
            #pragma unroll
            for (int p = 0; p < 4; ++p) {
                int cid = tid + p * 256;
                int d = cid >> 4, ch = cid & 15;
                bf16x8 vv2 = *(bf16x8*)&SMEM[d * 128 + ((ch ^ (d & 7)) << 3)];
                *(bf16x8*)&Vtg[((size_t)((bb * HH + hh) * 64 + d)) * (size_t)SS + sr + ch * 8] = vv2;
            }
        }
    }
}

// ---------------- Flash attention: S^T + permuted-V, 64-row Q tiles --------------
// grid 32x16x2 = 1024 blocks = 4 blocks/CU for latency hiding; each ds_read_b128
// feeds exactly one MFMA operand (no re-reads).
__global__ __launch_bounds__(256, 4) void attn_mfma(
    const unsigned short* __restrict__ qkv,
    const unsigned short* __restrict__ Vtg,   // [b][h][64][2048], virtual key order
    unsigned short* __restrict__ outb)
{
    __shared__ unsigned short Ks[128 * 64];
    __shared__ unsigned short VtL[64 * 128];
    int tid = threadIdx.x;
    int lane = tid & 63;
    int wv = tid >> 6;
    int qt = blockIdx.x, h = blockIdx.y, b = blockIdx.z;
    int col16 = lane & 15, quad = lane >> 4;

    const unsigned short* qbase = qkv + (size_t)(b * SS) * 3072;
    const unsigned short* Kg = qbase + h * 192 + 64;
    const unsigned short* Vg = Vtg + ((size_t)(b * HH + h) * 64) * (size_t)SS;

    // Q fragments, pre-scaled by 0.125*log2(e) so exp2 needs no multiply
    const float C = 0.18033688011112042f;
    int qrow = qt * 64 + wv * 16 + col16;
    bf16x8 qf[2];
    qf[0] = *(const bf16x8*)&qbase[(size_t)qrow * 3072 + h * 192 + quad * 8];
    qf[1] = *(const bf16x8*)&qbase[(size_t)qrow * 3072 + h * 192 + 32 + quad * 8];
    #pragma unroll
    for (int c = 0; c < 2; ++c)
        #pragma unroll
        for (int i = 0; i < 8; ++i) {
            float f = __uint_as_float(((unsigned)(unsigned short)qf[c][i]) << 16) * C;
            qf[c][i] = (short)f2bf(f);
        }

    f32x4 o[4] = {};
    float lsum = 0.f;

    for (int s0 = 0; s0 < SS; s0 += 128) {
        if (s0) __syncthreads();
        #pragma unroll
        for (int p = 0; p < 4; ++p) {
            int ci = (p * 4 + wv) * 64 + lane;
            int k = ci >> 3, sk = ci & 7, qk = sk ^ (k & 7);
            glds16(Kg + (size_t)(s0 + k) * 3072 + qk * 8, &Ks[ci * 8]);
            int dv = ci >> 4, sv = ci & 15, qv = sv ^ (dv & 7);
            glds16(Vg + (size_t)dv * SS + s0 + qv * 8, &VtL[ci * 8]);
        }
        __syncthreads();

        // ---- S^T: st[t][r] = (q.k)*C for key=16t+quad*4+r, q=col16 ----
        f32x4 st[8];
        #pragma unroll
        for (int t = 0; t < 8; ++t) {
            f32x4 z = {};
            st[t] = z;
            int key = t * 16 + col16;
            #pragma unroll
            for (int c = 0; c < 2; ++c) {
                bf16x8 kf = *(const bf16x8*)&Ks[key * 64 + (((c * 4 + quad) ^ (key & 7)) * 8)];
                st[t] = __builtin_amdgcn_mfma_f32_16x16x32_bf16(kf, qf[c], st[t], 0, 0, 0);
            }
        }

        // ---- exp2 + pack to bf16 pairs ----
        unsigned lo[8], hi[8];
        float psum = 0.f;
        #pragma unroll
        for (int t = 0; t < 8; ++t) {
            float p0 = __builtin_amdgcn_exp2f(st[t][0]);
            float p1 = __builtin_amdgcn_exp2f(st[t][1]);
            float p2 = __builtin_amdgcn_exp2f(st[t][2]);
            float p3 = __builtin_amdgcn_exp2f(st[t][3]);
            psum += (p0 + p1) + (p2 + p3);
            lo[t] = __builtin_amdgcn_perm(__float_as_uint(p1), __float_as_uint(p0), 0x07060302u);
            hi[t] = __builtin_amdgcn_perm(__float_as_uint(p3), __float_as_uint(p2), 0x07060302u);
        }
        psum += __shfl_xor(psum, 16);
        psum += __shfl_xor(psum, 32);
        lsum += psum;

        // ---- O += P @ V, P fragments direct from registers (virtual key order) --
        #pragma unroll
        for (int kc = 0; kc < 4; ++kc) {
            uint4 pk;
            pk.x = lo[2 * kc]; pk.y = hi[2 * kc];
            pk.z = lo[2 * kc + 1]; pk.w = hi[2 * kc + 1];
            bf16x8 pf = *(bf16x8*)&pk;
            #pragma unroll
            for (int nt = 0; nt < 4; ++nt) {
                int d = nt * 16 + col16;
                bf16x8 vf = *(const bf16x8*)&VtL[d * 128 + (((kc * 4 + quad) ^ (d & 7)) * 8)];
                o[nt] = __builtin_amdgcn_mfma_f32_16x16x32_bf16(pf, vf, o[nt], 0, 0, 0);
            }
        }
    }

    float linv = __builtin_amdgcn_rcpf(lsum);   // valid for q = col16
    float linv_r[4];
    #pragma unroll
    for (int r = 0; r < 4; ++r) linv_r[r] = __shfl(linv, quad * 4 + r);

    int orow0 = b * SS + qt * 64 + wv * 16;
    #pragma unroll
    for (int r = 0; r < 4; ++r) {
        int mm = orow0 + quad * 4 + r;
        #pragma unroll
        for (int nt = 0; nt < 4; ++nt)
            outb[(size_t)mm * DD + h * 64 + nt * 16 + col16] = f2bf(o[nt][r] * linv_r[r]);
    }
}

// ---------------------------------------------------------------------------------
extern "C" void kernel_launch(void* const* d_in, const int* in_sizes, int n_in,
                              void* d_out, int out_size, void* d_ws, size_t ws_size,
                              hipStream_t stream) {
    const float* x    = (const float*)d_in[0];
    const float* g1   = (const float*)d_in[1];
    const float* b1   = (const float*)d_in[2];
    const float* Wqkv = (const float*)d_in[3];
    const float* bqkv = (const float*)d_in[4];
    const float* Wo   = (const float*)d_in[5];
    const float* bo   = (const float*)d_in[6];
    const float* g2   = (const float*)d_in[7];
    const float* b2   = (const float*)d_in[8];
    const float* W1   = (const float*)d_in[9];
    const float* b1m  = (const float*)d_in[10];
    const float* W2   = (const float*)d_in[11];
    const float* b2m  = (const float*)d_in[12];
    float* out = (float*)d_out;

    char* wsb = (char*)d_ws;
    unsigned short* Wq_b  = (unsigned short*)(wsb);               // 0..6 MB
    unsigned short* Wo_b  = (unsigned short*)(wsb + 6291456);
    unsigned short* W1_b  = (unsigned short*)(wsb + 8388608);
    unsigned short* W2_b  = (unsigned short*)(wsb + 16777216);
    unsigned short* hb    = (unsigned short*)(wsb + 25165824);    // 24..32 MB bf16
    unsigned short* qkvb  = (unsigned short*)(wsb + 33554432);    // 32..56 MB bf16
    unsigned short* attnb = (unsigned short*)(wsb + 58720256);    // 56..64 MB bf16
    float*          x1    = (float*)(wsb + 67108864);             // 64..80 MB fp32
    unsigned short* ffb   = (unsigned short*)(wsb + 83886080);    // 80..112 MB bf16
    unsigned short* Vtg   = (unsigned short*)(wsb + 83886080);    // aliases ffb
    unsigned short* P0    = (unsigned short*)(wsb + 33554432);    // 32..40 MB (dead qkvb)
    unsigned short* P1    = (unsigned short*)(wsb + 41943040);    // 40..48 MB (dead qkvb)

    // prep: LN1 (4096 blocks) + weight casts (12288 blocks)
    prep_kernel<<<16384, 256, 0, stream>>>(x, g1, b1, hb,
                                           Wqkv, Wq_b, Wo, Wo_b, W1, W1_b, W2, W2_b);
    // 2. qkv = h @ Wqkv^T + bqkv ; V -> Vtg (virtual key order)
    gemm_nt_mfma<0,0,1,128,1,0,0,1><<<dim3(24, 32), 256, 0, stream>>>(hb, Wq_b, bqkv, nullptr, qkvb,
                                                                      nullptr, Vtg, NROWS, 3 * DD, DD);
    // 3. attention (64-row Q tiles, 4 blocks/CU)
    attn_mfma<<<dim3(SS / 64, HH, BB), 256, 0, stream>>>(qkvb, Vtg, attnb);
    // 4. x1 = x + attn @ Wo^T + bo
    gemm_nt_mfma<0,1,0,64,0,0,0,1><<<dim3(16, 32), 256, 0, stream>>>(attnb, Wo_b, bo, x, x1,
                                                                     nullptr, nullptr, NROWS, DD, DD);
    // 5. h = LN(x1)
    ln_kernel<<<NROWS, 256, 0, stream>>>(x1, g2, b2, hb);
    // 6. ff = gelu(h @ W1^T + b1m)
    gemm_nt_mfma<1,0,1,128,0,1,0,1><<<dim3(32, 32), 256, 0, stream>>>(hb, W1_b, b1m, nullptr, ffb,
                                                                      nullptr, nullptr, NROWS, FFDIM, DD);
    // 7. split-K partials (bf16): ff @ W2^T halves
    gemm_nt_mfma<0,0,0,128,0,0,1,1><<<dim3(8, 32, 2), 256, 0, stream>>>(ffb, W2_b, nullptr, nullptr, P0,
                                                                        P1, nullptr, NROWS, DD, FFDIM);
    // 8. out = x1 + P0 + P1 + b2m
    reduce_add<<<4096, 256, 0, stream>>>(x1, P0, P1, b2m, out);
}

// Round 9
// 317.253 us; speedup vs baseline: 1.0015x; 1.0015x over previous
//
#include <hip/hip_runtime.h>
#include <math.h>

#define BB 2
#define SS 2048
#define DD 1024
#define HH 16
#define FFDIM 4096
#define NROWS 4096

typedef short bf16x8 __attribute__((ext_vector_type(8)));
typedef float f32x4 __attribute__((ext_vector_type(4)));

__device__ __forceinline__ unsigned short f2bf(float f) {
    unsigned u = __float_as_uint(f);
    u += 0x7fffu + ((u >> 16) & 1u);
    return (unsigned short)(u >> 16);
}
__device__ __forceinline__ float bf2f(unsigned short s) {
    return __uint_as_float(((unsigned)s) << 16);
}

typedef __attribute__((address_space(1))) void gvoid;
typedef __attribute__((address_space(3))) void lvoid;
__device__ __forceinline__ void glds16(const void* g, void* l) {
    __builtin_amdgcn_global_load_lds((gvoid*)g, (lvoid*)l, 16, 0, 0);
}

// virtual key order: within each 32-key group, actual (16*t + quad*4 + r) sits at
// virtual (quad*8 + 4*t + r), t in {0,1}.
__device__ __forceinline__ int vkey(int kloc) {   // kloc % 4 == 0
    return (kloc & ~31) + ((kloc & 12) << 1) + ((kloc & 16) >> 2);
}

// ---------------- LN body (one block, row of 1024, fp32 -> bf16) -----------------
__device__ __forceinline__ void ln_body(const float* __restrict__ x,
                                        const float* __restrict__ g,
                                        const float* __restrict__ b,
                                        unsigned short* __restrict__ out, int row) {
    const float* xr = x + (size_t)row * DD;
    unsigned short* orow = out + (size_t)row * DD;
    int t = threadIdx.x;
    float4 v = ((const float4*)xr)[t];
    float s  = v.x + v.y + v.z + v.w;
    float s2 = v.x*v.x + v.y*v.y + v.z*v.z + v.w*v.w;
    #pragma unroll
    for (int off = 32; off > 0; off >>= 1) {
        s  += __shfl_down(s,  off);
        s2 += __shfl_down(s2, off);
    }
    __shared__ float red1[4], red2[4];
    int wid = t >> 6, lane = t & 63;
    if (lane == 0) { red1[wid] = s; red2[wid] = s2; }
    __syncthreads();
    if (t == 0) {
        float a = 0.f, a2 = 0.f;
        #pragma unroll
        for (int i = 0; i < 4; ++i) { a += red1[i]; a2 += red2[i]; }
        red1[0] = a; red2[0] = a2;
    }
    __syncthreads();
    float mean = red1[0] * (1.0f / DD);
    float var  = red2[0] * (1.0f / DD) - mean * mean;
    float rs = rsqrtf(var + 1e-5f);
    float4 gv = ((const float4*)g)[t];
    float4 bv = ((const float4*)b)[t];
    ushort4 o;
    o.x = f2bf((v.x - mean) * rs * gv.x + bv.x);
    o.y = f2bf((v.y - mean) * rs * gv.y + bv.y);
    o.z = f2bf((v.z - mean) * rs * gv.z + bv.z);
    o.w = f2bf((v.w - mean) * rs * gv.w + bv.w);
    ((ushort4*)orow)[t] = o;
}

__global__ __launch_bounds__(256) void ln_kernel(const float* __restrict__ x,
                                                 const float* __restrict__ g,
                                                 const float* __restrict__ b,
                                                 unsigned short* __restrict__ out) {
    ln_body(x, g, b, out, blockIdx.x);
}

// ---------------- prep: LN1 (blocks 0..4095) + 4 weight casts --------------------
__global__ __launch_bounds__(256) void prep_kernel(
    const float* __restrict__ x, const float* __restrict__ g1,
    const float* __restrict__ b1, unsigned short* __restrict__ hb,
    const float* __restrict__ a, unsigned short* __restrict__ oa,
    const float* __restrict__ b, unsigned short* __restrict__ ob,
    const float* __restrict__ c, unsigned short* __restrict__ oc,
    const float* __restrict__ d, unsigned short* __restrict__ od) {
    if (blockIdx.x < 4096) { ln_body(x, g1, b1, hb, blockIdx.x); return; }
    int i = (blockIdx.x - 4096) * 256 + threadIdx.x;
    const float* src; unsigned short* dst; int off;
    if (i < 786432)       { src = a; dst = oa; off = i; }
    else if (i < 1048576) { src = b; dst = ob; off = i - 786432; }
    else if (i < 2097152) { src = c; dst = oc; off = i - 1048576; }
    else                  { src = d; dst = od; off = i - 2097152; }
    float4 v = ((const float4*)src)[off];
    ushort4 o;
    o.x = f2bf(v.x); o.y = f2bf(v.y); o.z = f2bf(v.z); o.w = f2bf(v.w);
    ((ushort4*)dst)[off] = o;
}

// ---------------- final reduce: out = x1 + P0 + P1 + bias (P bf16) ---------------
__global__ __launch_bounds__(256) void reduce_add(const float* __restrict__ x1,
                                                  const unsigned short* __restrict__ P0,
                                                  const unsigned short* __restrict__ P1,
                                                  const float* __restrict__ bias,
                                                  float* __restrict__ out) {
    int i = blockIdx.x * 256 + threadIdx.x;      // float4 index over 4096x1024
    float4 a = ((const float4*)x1)[i];
    ushort4 p = ((const ushort4*)P0)[i];
    ushort4 q = ((const ushort4*)P1)[i];
    float4 bv = ((const float4*)bias)[i & 255];
    float4 o;
    o.x = a.x + bf2f(p.x) + bf2f(q.x) + bv.x;
    o.y = a.y + bf2f(p.y) + bf2f(q.y) + bv.y;
    o.z = a.z + bf2f(p.z) + bf2f(q.z) + bv.z;
    o.w = a.w + bf2f(p.w) + bf2f(q.w) + bv.w;
    ((float4*)out)[i] = o;
}

// ---------------- bf16 MFMA NT GEMM, tile 128 x TN -------------------------------
// VT: QKV mode; CS: coalesced bf16 store via LDS (FF1); SPLITK: 2-way K-split with
// bf16 partials; SWZ: XCD-locality block remap (same M-band -> same XCD).
template<int ACT, int RES, int OUTBF, int TN, int VT, int CS, int SPLITK, int SWZ>
__global__ __launch_bounds__(256, 3) void gemm_nt_mfma(
    const unsigned short* __restrict__ A,
    const unsigned short* __restrict__ W,
    const float* __restrict__ bias,
    const float* __restrict__ res,
    void* __restrict__ Cout,
    void* __restrict__ Cout2,
    unsigned short* __restrict__ Vtg,
    int M, int N, int K)
{
    constexpr int MI = (TN == 128) ? 4 : 2;
    constexpr int WR = TN / 4;
    __shared__ unsigned short SMEM[128 * 64 + TN * 64];
    unsigned short* As = SMEM;
    unsigned short* Ws = SMEM + 128 * 64;
    int tid = threadIdx.x;
    int lane = tid & 63;
    int w = tid >> 6;
    int rowbase = (TN == 128) ? ((w >> 1) * 64) : (w * 32);
    int colbase = (TN == 128) ? ((w & 1) * 64) : 0;
    int col16 = lane & 15, quad = lane >> 4;

    int bx, by, bz;
    if constexpr (SWZ) {
        // assumes round-robin block->XCD; keeps all (n,z) of an M-band on one XCD
        int nx = gridDim.x, nz = gridDim.z;
        int bid = blockIdx.x + nx * (blockIdx.y + 32 * blockIdx.z);
        int xcd = bid & 7;
        int g = bid >> 3;
        int per = nx * nz;
        by = xcd + 8 * (g / per);
        int r = g % per;
        bx = r % nx;
        bz = r / nx;
    } else { bx = blockIdx.x; by = blockIdx.y; bz = blockIdx.z; }
    int bm = by * 128, bn = bx * TN;

    int klen = SPLITK ? (K >> 1) : K;
    int kbase = SPLITK ? (bz * klen) : 0;

    f32x4 acc[MI][4] = {};

    int lrow = lane >> 3;
    int sw = (lane & 7) ^ lrow;
    const unsigned short* Ag = A + (size_t)(bm + w * 32 + lrow) * K + sw * 8;
    const unsigned short* Wg = W + (size_t)(bn + w * WR + lrow) * K + sw * 8;

    for (int k0 = kbase; k0 < kbase + klen; k0 += 64) {
        if (k0 != kbase) __syncthreads();
        #pragma unroll
        for (int it = 0; it < 4; ++it)
            glds16(Ag + (size_t)(8 * it) * K + k0, &As[(w * 32 + 8 * it) * 64]);
        #pragma unroll
        for (int it = 0; it < WR / 8; ++it)
            glds16(Wg + (size_t)(8 * it) * K + k0, &Ws[(w * WR + 8 * it) * 64]);
        __syncthreads();
        #pragma unroll
        for (int c = 0; c < 2; ++c) {
            bf16x8 af[MI], bfr[4];
            #pragma unroll
            for (int i = 0; i < MI; ++i) {
                int m = rowbase + i * 16 + col16;
                af[i] = *(const bf16x8*)&As[m * 64 + (((c * 4 + quad) ^ (m & 7)) * 8)];
            }
            #pragma unroll
            for (int j = 0; j < 4; ++j) {
                int n = colbase + j * 16 + col16;
                bfr[j] = *(const bf16x8*)&Ws[n * 64 + (((c * 4 + quad) ^ (n & 7)) * 8)];
            }
            #pragma unroll
            for (int i = 0; i < MI; ++i)
                #pragma unroll
                for (int j = 0; j < 4; ++j)
                    acc[i][j] = __builtin_amdgcn_mfma_f32_16x16x32_bf16(af[i], bfr[j], acc[i][j], 0, 0, 0);
        }
    }

    if constexpr (SPLITK) {
        unsigned short* P = (unsigned short*)(bz ? Cout2 : Cout);
        #pragma unroll
        for (int i = 0; i < MI; ++i) {
            #pragma unroll
            for (int j = 0; j < 4; ++j) {
                int nn = bn + colbase + j * 16 + col16;
                #pragma unroll
                for (int r = 0; r < 4; ++r) {
                    int mm = bm + rowbase + i * 16 + quad * 4 + r;
                    P[(size_t)mm * N + nn] = f2bf(acc[i][j][r]);
                }
            }
        }
        return;
    }

    if constexpr (CS) {
        // ---- FF1: bias+gelu -> LDS (swizzled) -> coalesced b128 stores ----
        __syncthreads();
        #pragma unroll
        for (int i = 0; i < MI; ++i) {
            #pragma unroll
            for (int j = 0; j < 4; ++j) {
                int nl = colbase + j * 16 + col16;
                float bv = bias[bn + nl];
                int c = nl >> 4;
                #pragma unroll
                for (int r = 0; r < 4; ++r) {
                    int ml = rowbase + i * 16 + quad * 4 + r;
                    float v = acc[i][j][r] + bv;
                    if (ACT) {
                        float z = v * (1.595769122f + 0.071354816f * v * v);
                        float e = __builtin_amdgcn_exp2f(-z * 1.442695041f);
                        v = v * __builtin_amdgcn_rcpf(1.0f + e);
                    }
                    SMEM[ml * 128 + ((c ^ ((ml >> 2) & 7)) << 4) + (nl & 15)] = f2bf(v);
                }
            }
        }
        __syncthreads();
        #pragma unroll
        for (int p = 0; p < 8; ++p) {
            int cid = tid + p * 256;
            int row = cid >> 4, cc = cid & 15;
            int cs2 = cc >> 1;
            bf16x8 vv = *(bf16x8*)&SMEM[row * 128 + ((cs2 ^ ((row >> 2) & 7)) << 4) + (cc & 1) * 8];
            *(bf16x8*)&((unsigned short*)Cout)[(size_t)(bm + row) * N + bn + cc * 8] = vv;
        }
        return;
    }

    bool wave_v = VT && ((((bn + colbase) >> 6) % 3) == 2);
    if constexpr (VT) __syncthreads();

    #pragma unroll
    for (int i = 0; i < MI; ++i) {
        #pragma unroll
        for (int j = 0; j < 4; ++j) {
            int nn = bn + colbase + j * 16 + col16;
            float bv = bias[nn];
            float vv[4];
            #pragma unroll
            for (int r = 0; r < 4; ++r) {
                float v = acc[i][j][r] + bv;
                if (ACT) {
                    float z = v * (1.595769122f + 0.071354816f * v * v);
                    float e = __builtin_amdgcn_exp2f(-z * 1.442695041f);
                    v = v * __builtin_amdgcn_rcpf(1.0f + e);
                }
                vv[r] = v;
            }
            int mm0 = bm + rowbase + i * 16 + quad * 4;
            if (VT && wave_v) {
                int d = j * 16 + col16;
                int kloc = rowbase + i * 16 + quad * 4;
                int vl = vkey(kloc);
                int ch = vl >> 3;
                ushort4 pk;
                pk.x = f2bf(vv[0]); pk.y = f2bf(vv[1]);
                pk.z = f2bf(vv[2]); pk.w = f2bf(vv[3]);
                *(ushort4*)&SMEM[d * 128 + ((ch ^ (d & 7)) << 3) + (vl & 7)] = pk;
            } else {
                #pragma unroll
                for (int r = 0; r < 4; ++r) {
                    int mm = mm0 + r;
                    float v = vv[r];
                    if (RES) v += res[(size_t)mm * N + nn];
                    if (OUTBF) ((unsigned short*)Cout)[(size_t)mm * N + nn] = f2bf(v);
                    else       ((float*)Cout)[(size_t)mm * N + nn] = v;
                }
            }
        }
    }

    if constexpr (VT) {
        __syncthreads();
        bool g0v = ((bn >> 6) % 3) == 2;
        bool g1v = (((bn + 64) >> 6) % 3) == 2;
        if (g0v || g1v) {
            int vcb = g0v ? 0 : 64;
            int hh = (bn + vcb) / 192;
            int bb = bm >> 11, sr = bm & 2047;
            #pragma unroll
            for (int p = 0; p < 4; ++p) {
                int cid = tid + p * 256;
                int d = cid >> 4, ch = cid & 15;
                bf16x8 vv2 = *(bf16x8*)&SMEM[d * 128 + ((ch ^ (d & 7)) << 3)];
                *(bf16x8*)&Vtg[((size_t)((bb * HH + hh) * 64 + d)) * (size_t)SS + sr + ch * 8] = vv2;
            }
        }
    }
}

// ---------------- Flash attention: S^T + permuted-V, 128-row Q, fragment reuse ---
// Wave owns TWO 16-row q sub-tiles; each kf/vf LDS read feeds BOTH sub-tiles'
// MFMAs (qq-inner), halving LDS bytes per FLOP vs the 64-row version.
__global__ __launch_bounds__(256, 2) void attn_mfma(
    const unsigned short* __restrict__ qkv,
    const unsigned short* __restrict__ Vtg,   // [b][h][64][2048], virtual key order
    unsigned short* __restrict__ outb)
{
    __shared__ unsigned short Ks[128 * 64];
    __shared__ unsigned short VtL[64 * 128];
    int tid = threadIdx.x;
    int lane = tid & 63;
    int wv = tid >> 6;
    int qt = blockIdx.x, h = blockIdx.y, b = blockIdx.z;
    int col16 = lane & 15, quad = lane >> 4;

    const unsigned short* qbase = qkv + (size_t)(b * SS) * 3072;
    const unsigned short* Kg = qbase + h * 192 + 64;
    const unsigned short* Vg = Vtg + ((size_t)(b * HH + h) * 64) * (size_t)SS;

    // Q fragments for 2 sub-tiles, pre-scaled by 0.125*log2(e)
    const float C = 0.18033688011112042f;
    bf16x8 qf[2][2];
    #pragma unroll
    for (int qq = 0; qq < 2; ++qq) {
        int qrow = qt * 128 + qq * 64 + wv * 16 + col16;
        qf[qq][0] = *(const bf16x8*)&qbase[(size_t)qrow * 3072 + h * 192 + quad * 8];
        qf[qq][1] = *(const bf16x8*)&qbase[(size_t)qrow * 3072 + h * 192 + 32 + quad * 8];
        #pragma unroll
        for (int c = 0; c < 2; ++c)
            #pragma unroll
            for (int i = 0; i < 8; ++i) {
                float f = __uint_as_float(((unsigned)(unsigned short)qf[qq][c][i]) << 16) * C;
                qf[qq][c][i] = (short)f2bf(f);
            }
    }

    f32x4 o[2][4] = {};
    float lsum[2] = {0.f, 0.f};

    for (int s0 = 0; s0 < SS; s0 += 128) {
        if (s0) __syncthreads();
        #pragma unroll
        for (int p = 0; p < 4; ++p) {
            int ci = (p * 4 + wv) * 64 + lane;
            int k = ci >> 3, sk = ci & 7, qk = sk ^ (k & 7);
            glds16(Kg + (size_t)(s0 + k) * 3072 + qk * 8, &Ks[ci * 8]);
            int dv = ci >> 4, sv = ci & 15, qv = sv ^ (dv & 7);
            glds16(Vg + (size_t)dv * SS + s0 + qv * 8, &VtL[ci * 8]);
        }
        __syncthreads();

        // ---- S^T phase: each kf read feeds both q sub-tiles ----
        f32x4 st[2][8];
        #pragma unroll
        for (int t = 0; t < 8; ++t) {
            f32x4 z = {};
            st[0][t] = z; st[1][t] = z;
            int key = t * 16 + col16;
            #pragma unroll
            for (int c = 0; c < 2; ++c) {
                bf16x8 kf = *(const bf16x8*)&Ks[key * 64 + (((c * 4 + quad) ^ (key & 7)) * 8)];
                st[0][t] = __builtin_amdgcn_mfma_f32_16x16x32_bf16(kf, qf[0][c], st[0][t], 0, 0, 0);
                st[1][t] = __builtin_amdgcn_mfma_f32_16x16x32_bf16(kf, qf[1][c], st[1][t], 0, 0, 0);
            }
        }

        // ---- exp2 + pack to bf16 pairs (both sub-tiles) ----
        unsigned plo[2][8], phi[2][8];
        #pragma unroll
        for (int qq = 0; qq < 2; ++qq) {
            float psum = 0.f;
            #pragma unroll
            for (int t = 0; t < 8; ++t) {
                float p0 = __builtin_amdgcn_exp2f(st[qq][t][0]);
                float p1 = __builtin_amdgcn_exp2f(st[qq][t][1]);
                float p2 = __builtin_amdgcn_exp2f(st[qq][t][2]);
                float p3 = __builtin_amdgcn_exp2f(st[qq][t][3]);
                psum += (p0 + p1) + (p2 + p3);
                plo[qq][t] = __builtin_amdgcn_perm(__float_as_uint(p1), __float_as_uint(p0), 0x07060302u);
                phi[qq][t] = __builtin_amdgcn_perm(__float_as_uint(p3), __float_as_uint(p2), 0x07060302u);
            }
            psum += __shfl_xor(psum, 16);
            psum += __shfl_xor(psum, 32);
            lsum[qq] += psum;
        }

        // ---- PV phase: each vf read feeds both q sub-tiles ----
        #pragma unroll
        for (int kc = 0; kc < 4; ++kc) {
            uint4 pk0, pk1;
            pk0.x = plo[0][2*kc]; pk0.y = phi[0][2*kc];
            pk0.z = plo[0][2*kc+1]; pk0.w = phi[0][2*kc+1];
            pk1.x = plo[1][2*kc]; pk1.y = phi[1][2*kc];
            pk1.z = plo[1][2*kc+1]; pk1.w = phi[1][2*kc+1];
            bf16x8 pf0 = *(bf16x8*)&pk0;
            bf16x8 pf1 = *(bf16x8*)&pk1;
            #pragma unroll
            for (int nt = 0; nt < 4; ++nt) {
                int d = nt * 16 + col16;
                bf16x8 vf = *(const bf16x8*)&VtL[d * 128 + (((kc * 4 + quad) ^ (d & 7)) * 8)];
                o[0][nt] = __builtin_amdgcn_mfma_f32_16x16x32_bf16(pf0, vf, o[0][nt], 0, 0, 0);
                o[1][nt] = __builtin_amdgcn_mfma_f32_16x16x32_bf16(pf1, vf, o[1][nt], 0, 0, 0);
            }
        }
    }

    #pragma unroll
    for (int qq = 0; qq < 2; ++qq) {
        float linv = __builtin_amdgcn_rcpf(lsum[qq]);   // valid for q = col16
        float linv_r[4];
        #pragma unroll
        for (int r = 0; r < 4; ++r) linv_r[r] = __shfl(linv, quad * 4 + r);
        int orow0 = b * SS + qt * 128 + qq * 64 + wv * 16;
        #pragma unroll
        for (int r = 0; r < 4; ++r) {
            int mm = orow0 + quad * 4 + r;
            #pragma unroll
            for (int nt = 0; nt < 4; ++nt)
                outb[(size_t)mm * DD + h * 64 + nt * 16 + col16] = f2bf(o[qq][nt][r] * linv_r[r]);
        }
    }
}

// ---------------------------------------------------------------------------------
extern "C" void kernel_launch(void* const* d_in, const int* in_sizes, int n_in,
                              void* d_out, int out_size, void* d_ws, size_t ws_size,
                              hipStream_t stream) {
    const float* x    = (const float*)d_in[0];
    const float* g1   = (const float*)d_in[1];
    const float* b1   = (const float*)d_in[2];
    const float* Wqkv = (const float*)d_in[3];
    const float* bqkv = (const float*)d_in[4];
    const float* Wo   = (const float*)d_in[5];
    const float* bo   = (const float*)d_in[6];
    const float* g2   = (const float*)d_in[7];
    const float* b2   = (const float*)d_in[8];
    const float* W1   = (const float*)d_in[9];
    const float* b1m  = (const float*)d_in[10];
    const float* W2   = (const float*)d_in[11];
    const float* b2m  = (const float*)d_in[12];
    float* out = (float*)d_out;

    char* wsb = (char*)d_ws;
    unsigned short* Wq_b  = (unsigned short*)(wsb);               // 0..6 MB
    unsigned short* Wo_b  = (unsigned short*)(wsb + 6291456);
    unsigned short* W1_b  = (unsigned short*)(wsb + 8388608);
    unsigned short* W2_b  = (unsigned short*)(wsb + 16777216);
    unsigned short* hb    = (unsigned short*)(wsb + 25165824);    // 24..32 MB bf16
    unsigned short* qkvb  = (unsigned short*)(wsb + 33554432);    // 32..56 MB bf16
    unsigned short* attnb = (unsigned short*)(wsb + 58720256);    // 56..64 MB bf16
    float*          x1    = (float*)(wsb + 67108864);             // 64..80 MB fp32
    unsigned short* ffb   = (unsigned short*)(wsb + 83886080);    // 80..112 MB bf16
    unsigned short* Vtg   = (unsigned short*)(wsb + 83886080);    // aliases ffb
    unsigned short* P0    = (unsigned short*)(wsb + 33554432);    // 32..40 MB (dead qkvb)
    unsigned short* P1    = (unsigned short*)(wsb + 41943040);    // 40..48 MB (dead qkvb)

    // prep: LN1 (4096 blocks) + weight casts (12288 blocks)
    prep_kernel<<<16384, 256, 0, stream>>>(x, g1, b1, hb,
                                           Wqkv, Wq_b, Wo, Wo_b, W1, W1_b, W2, W2_b);
    // 2. qkv = h @ Wqkv^T + bqkv ; V -> Vtg (virtual key order)
    gemm_nt_mfma<0,0,1,128,1,0,0,1><<<dim3(24, 32), 256, 0, stream>>>(hb, Wq_b, bqkv, nullptr, qkvb,
                                                                      nullptr, Vtg, NROWS, 3 * DD, DD);
    // 3. attention (128-row Q tiles, kf/vf reuse across sub-tiles)
    attn_mfma<<<dim3(SS / 128, HH, BB), 256, 0, stream>>>(qkvb, Vtg, attnb);
    // 4. x1 = x + attn @ Wo^T + bo
    gemm_nt_mfma<0,1,0,64,0,0,0,1><<<dim3(16, 32), 256, 0, stream>>>(attnb, Wo_b, bo, x, x1,
                                                                     nullptr, nullptr, NROWS, DD, DD);
    // 5. h = LN(x1)
    ln_kernel<<<NROWS, 256, 0, stream>>>(x1, g2, b2, hb);
    // 6. ff = gelu(h @ W1^T + b1m)
    gemm_nt_mfma<1,0,1,128,0,1,0,1><<<dim3(32, 32), 256, 0, stream>>>(hb, W1_b, b1m, nullptr, ffb,
                                                                      nullptr, nullptr, NROWS, FFDIM, DD);
    // 7. split-K partials (bf16): ff @ W2^T halves
    gemm_nt_mfma<0,0,0,128,0,0,1,1><<<dim3(8, 32, 2), 256, 0, stream>>>(ffb, W2_b, nullptr, nullptr, P0,
                                                                        P1, nullptr, NROWS, DD, FFDIM);
    // 8. out = x1 + P0 + P1 + b2m
    reduce_add<<<4096, 256, 0, stream>>>(x1, P0, P1, b2m, out);
}